// Round 7
// baseline (564.667 us; speedup 1.0000x reference)
//
#include <hip/hip_runtime.h>
#include <hip/hip_bf16.h>
#include <stdint.h>

#define AS1 __attribute__((address_space(1)))
#define AS3 __attribute__((address_space(3)))

typedef float f32x4 __attribute__((ext_vector_type(4)));
typedef __bf16 bf16x8 __attribute__((ext_vector_type(8)));

static __device__ __forceinline__ unsigned short f2bf(float f) {
  unsigned u = __float_as_uint(f);
  u += 0x7fff + ((u >> 16) & 1);   // RNE
  return (unsigned short)(u >> 16);
}
static __device__ __forceinline__ float bf2f_lo(unsigned u) { return __uint_as_float(u << 16); }
static __device__ __forceinline__ float bf2f_hi(unsigned u) { return __uint_as_float(u & 0xffff0000u); }

// ---------------- conversion kernels ----------------

__global__ __launch_bounds__(256) void k_f32_to_bf16(const float* __restrict__ in,
                                                     unsigned short* __restrict__ out, int n4) {
  int i = blockIdx.x * 256 + threadIdx.x;
  if (i >= n4) return;
  float4 v = reinterpret_cast<const float4*>(in)[i];
  ushort4 o;
  o.x = f2bf(v.x); o.y = f2bf(v.y); o.z = f2bf(v.z); o.w = f2bf(v.w);
  reinterpret_cast<ushort4*>(out)[i] = o;
}

// transpose + convert the four 512x512 weights: out[n*512+k] = bf16(w[k*512+n])
__global__ __launch_bounds__(256) void k_wtrans(const float* __restrict__ w0, const float* __restrict__ w1,
                                                const float* __restrict__ w2, const float* __restrict__ w3,
                                                unsigned short* __restrict__ o0, unsigned short* __restrict__ o1,
                                                unsigned short* __restrict__ o2, unsigned short* __restrict__ o3) {
  const float* w; unsigned short* o;
  switch (blockIdx.y) {
    case 0: w = w0; o = o0; break;
    case 1: w = w1; o = o1; break;
    case 2: w = w2; o = o2; break;
    default: w = w3; o = o3; break;
  }
  int idx = blockIdx.x * 256 + threadIdx.x;   // 0..262143
  int kk = idx >> 9;
  int n  = idx & 511;
  o[n * 512 + kk] = f2bf(w[idx]);
}

// ---------------- GEMM: C[M,N] = A[M,K] * Bt[N,K]^T (+bias) ----------------
// m97 structure: 128x128 tile, BK=32, 4 waves, global_load_lds width 16,
// mfma_f32_16x16x32_bf16. C frag layout col=lane&15, row=(lane>>4)*4+reg.
// All grids have nwg%8==0 -> bijective XCD swizzle (T1).
// EPI: 0 = bf16 out
//      1 = f32 out (also split-K partials)
//      2 = dual KV: cols 0-511 -> bf16 K ; cols 512-1023 -> V^T scatter
//      3 = bf16(exp(v)) via LDS re-stage -> 16B coalesced stores; per-thread
//          32-col row-sum partials to Cout2[bx*4+chunk][4096] (no shuffles)
// SPLITK: bz picks a kLen K-chunk, f32 partial at CoutF + bz*partStride.

template<int EPI, int HAS_BIAS, int SPLITK>
__global__ __launch_bounds__(256) void k_gemm_bt(
    const unsigned short* __restrict__ A, int lda,
    const unsigned short* __restrict__ Bt, int ldb,
    const float* __restrict__ bias, const float* __restrict__ bias2,
    void* __restrict__ Cout, void* __restrict__ Cout2,
    int ldc, int kLen, int partStride)
{
  // 17408 B: sA = [0,8KB), sB = [8KB,16KB); EPI=3 reuses all of it as
  // sC[64][136] (136 = 128 + 8-short pad: keeps 16B alignment, breaks the
  // 16-way bank conflict of a 256B row stride)
  __shared__ __align__(16) unsigned short smem[8704];
  unsigned short* sA = smem;
  unsigned short* sB = smem + 4096;

  // XCD-aware swizzle (bijective since nwg % 8 == 0)
  const int nx = gridDim.x, ny = gridDim.y;
  const int nwg = nx * ny * gridDim.z;
  const int bid = blockIdx.x + nx * (blockIdx.y + ny * blockIdx.z);
  const int wg = (bid & 7) * (nwg >> 3) + (bid >> 3);
  const int bx = wg % nx;
  const int tmp = wg / nx;
  const int by = tmp % ny;
  const int bz = tmp / ny;

  float* CoutF = (float*)Cout;
  if (SPLITK) {
    A  += (size_t)bz * kLen;
    Bt += (size_t)bz * kLen;
    CoutF += (size_t)bz * partStride;
  }

  const int tid = threadIdx.x;
  const int tileM = by * 128;
  const int tileN = bx * 128;
  const unsigned short* Ab = A + (size_t)tileM * lda;
  const unsigned short* Bb = Bt + (size_t)tileN * ldb;

  f32x4 acc[4][4];
#pragma unroll
  for (int m = 0; m < 4; ++m)
#pragma unroll
    for (int n = 0; n < 4; ++n)
      acc[m][n] = (f32x4){0.f, 0.f, 0.f, 0.f};

  const int lane = tid & 63;
  const int w = tid >> 6;
  const int wr = (w >> 1) * 64;
  const int wc = (w & 1) * 64;
  const int fr = lane & 15;
  const int fk = (lane >> 4) * 8;

  for (int k0 = 0; k0 < kLen; k0 += 32) {
    __syncthreads();
#pragma unroll
    for (int i = 0; i < 2; ++i) {
      int c = tid + i * 256;         // 0..511 (16B chunks)
      int r = c >> 2;
      int cb = (c & 3) * 8;
      __builtin_amdgcn_global_load_lds((const AS1 void*)(Ab + (size_t)r * lda + k0 + cb),
                                       (AS3 void*)(&sA[c * 8]), 16, 0, 0);
      __builtin_amdgcn_global_load_lds((const AS1 void*)(Bb + (size_t)r * ldb + k0 + cb),
                                       (AS3 void*)(&sB[c * 8]), 16, 0, 0);
    }
    __syncthreads();

    bf16x8 af[4], bfr[4];
#pragma unroll
    for (int m = 0; m < 4; ++m)
      af[m] = *reinterpret_cast<const bf16x8*>(&sA[(wr + m * 16 + fr) * 32 + fk]);
#pragma unroll
    for (int n = 0; n < 4; ++n)
      bfr[n] = *reinterpret_cast<const bf16x8*>(&sB[(wc + n * 16 + fr) * 32 + fk]);
#pragma unroll
    for (int m = 0; m < 4; ++m)
#pragma unroll
      for (int n = 0; n < 4; ++n)
        acc[m][n] = __builtin_amdgcn_mfma_f32_16x16x32_bf16(af[m], bfr[n], acc[m][n], 0, 0, 0);
  }

  const int col4 = lane & 15;
  const int rw4 = (lane >> 4) * 4;

  if (EPI == 3) {
    // LDS re-stage epilogue: 2 passes of 64 rows through sC[64][136]
    float* lsumPart = (float*)Cout2;
    const int lrow = tid >> 2;        // 0..63
    const int chunk = tid & 3;        // 32 cols each
    __syncthreads();                  // all waves done with sA/sB
#pragma unroll
    for (int pass = 0; pass < 2; ++pass) {
      if ((w >> 1) == pass) {
        // this wave's rows are local rows m*16+rw4+j of this pass
#pragma unroll
        for (int m = 0; m < 4; ++m)
#pragma unroll
          for (int n = 0; n < 4; ++n)
#pragma unroll
            for (int j = 0; j < 4; ++j)
              smem[(m * 16 + rw4 + j) * 136 + wc + n * 16 + col4] =
                  f2bf(__expf(acc[m][n][j]));
      }
      __syncthreads();
      const int gro = tileM + pass * 64 + lrow;
      float rs = 0.f;
#pragma unroll
      for (int i = 0; i < 4; ++i) {
        uint4 u = *reinterpret_cast<const uint4*>(&smem[lrow * 136 + chunk * 32 + i * 8]);
        rs += bf2f_lo(u.x) + bf2f_hi(u.x) + bf2f_lo(u.y) + bf2f_hi(u.y)
            + bf2f_lo(u.z) + bf2f_hi(u.z) + bf2f_lo(u.w) + bf2f_hi(u.w);
        *reinterpret_cast<uint4*>((unsigned short*)Cout + (size_t)gro * ldc
                                  + tileN + chunk * 32 + i * 8) = u;
      }
      lsumPart[(size_t)(bx * 4 + chunk) * 4096 + gro] = rs;
      __syncthreads();
    }
  } else {
#pragma unroll
    for (int n = 0; n < 4; ++n) {
      const int gc = tileN + wc + n * 16 + col4;
      float bval = 0.f;
      if (HAS_BIAS) bval = (EPI == 2) ? (gc < 512 ? bias[gc] : bias2[gc - 512]) : bias[gc];
#pragma unroll
      for (int m = 0; m < 4; ++m) {
        const int gr0 = tileM + wr + m * 16 + rw4;
#pragma unroll
        for (int j = 0; j < 4; ++j) {
          const int gr = gr0 + j;
          float v = acc[m][n][j] + bval;
          if (EPI == 1) {
            CoutF[(size_t)gr * ldc + gc] = v;
          } else if (EPI == 0) {
            ((unsigned short*)Cout)[(size_t)gr * ldc + gc] = f2bf(v);
          } else {  // EPI == 2: dual K | V^T
            if (gc < 512) {
              ((unsigned short*)Cout)[(size_t)gr * 512 + gc] = f2bf(v);
            } else {
              ((unsigned short*)Cout2)[((size_t)(gr >> 12)) * 2097152u
                                       + (size_t)(gc - 512) * 4096u
                                       + (size_t)(gr & 4095)] = f2bf(v);
            }
          }
        }
      }
    }
  }
}

// ---------------- invl[row] = 1 / sum_slot lsumPart[slot][row] ----------------

__global__ __launch_bounds__(256) void k_invl(const float* __restrict__ lsumPart,
                                              float* __restrict__ invl) {
  const int row = blockIdx.x * 256 + threadIdx.x;   // 4096 rows, 16 blocks
  float s = 0.f;
#pragma unroll
  for (int i = 0; i < 128; ++i) s += lsumPart[(size_t)i * 4096 + row];
  invl[row] = 1.0f / s;
}

// ------- split-K reduce + softmax normalization: ctx = bf16(sum * invl) ------

template<int NS>
__global__ __launch_bounds__(256) void k_reduce_ks(const float* __restrict__ part,
                                                   const float* __restrict__ invl,
                                                   unsigned short* __restrict__ out) {
  const int i = blockIdx.x * 256 + threadIdx.x;       // float4 index, 524288 total
  const float4* p = reinterpret_cast<const float4*>(part);
  float sx = 0.f, sy = 0.f, sz = 0.f, sw = 0.f;
#pragma unroll
  for (int z = 0; z < NS; ++z) {
    float4 a = p[i + (size_t)z * 524288];
    sx += a.x; sy += a.y; sz += a.z; sw += a.w;
  }
  const float iv = invl[i >> 7];                      // 128 float4 per 512-col row
  ushort4 o;
  o.x = f2bf(sx * iv); o.y = f2bf(sy * iv);
  o.z = f2bf(sz * iv); o.w = f2bf(sw * iv);
  reinterpret_cast<ushort4*>(out)[i] = o;
}

// ---------------- launch ----------------

extern "C" void kernel_launch(void* const* d_in, const int* in_sizes, int n_in,
                              void* d_out, int out_size, void* d_ws, size_t ws_size,
                              hipStream_t stream) {
  const float* query  = (const float*)d_in[0];
  const float* target = (const float*)d_in[1];
  const float* wq = (const float*)d_in[2];
  const float* bq = (const float*)d_in[3];
  const float* wk = (const float*)d_in[4];
  const float* bk = (const float*)d_in[5];
  const float* wv = (const float*)d_in[6];
  const float* bv = (const float*)d_in[7];
  const float* wo = (const float*)d_in[8];
  const float* bo = (const float*)d_in[9];
  float* out = (float*)d_out;

  const size_t SZ_BF = (size_t)16384 * 512 * 2;       // 16 MB

  char* ws = (char*)d_ws;
  size_t off = 0;
  unsigned short* query_bf  = (unsigned short*)(ws + off); off += SZ_BF;
  unsigned short* target_bf = (unsigned short*)(ws + off); off += SZ_BF;
  unsigned short* q_bf = (unsigned short*)(ws + off); off += SZ_BF;
  unsigned short* k_bf = (unsigned short*)(ws + off); off += SZ_BF;
  unsigned short* v_t  = (unsigned short*)(ws + off); off += SZ_BF;   // [B][512][4096]
  unsigned short* ctx  = (unsigned short*)(ws + off); off += SZ_BF;
  unsigned short* wq_t  = (unsigned short*)(ws + off); off += 512 * 512 * 2;
  unsigned short* wkv_t = (unsigned short*)(ws + off); off += 2 * 512 * 512 * 2;
  unsigned short* wo_t  = (unsigned short*)(ws + off); off += 512 * 512 * 2;
  unsigned short* Sbuf  = (unsigned short*)(ws + off); off += (size_t)4096 * 4096 * 2;  // 32 MB
  float* lsumPart = (float*)(ws + off); off += (size_t)128 * 4096 * 4;                  // 2 MB
  float* invl = (float*)(ws + off); off += 4096 * sizeof(float);
  (void)ws_size;

  // split-K partial buffer (4 x 4096x512 f32 = 32 MB): aliases query_bf/target_bf,
  // which are dead after the projection GEMMs complete (stream-ordered).
  float* part = (float*)ws;

  // 1) inputs -> bf16; weights -> bf16 transposed ([N][K])
  k_f32_to_bf16<<<8192, 256, 0, stream>>>(query,  query_bf,  2097152);
  k_f32_to_bf16<<<8192, 256, 0, stream>>>(target, target_bf, 2097152);
  k_wtrans<<<dim3(1024, 4), 256, 0, stream>>>(wq, wk, wv, wo,
                                              wq_t, wkv_t, wkv_t + 512 * 512, wo_t);

  // 2) projections  (M=16384, K=512)
  k_gemm_bt<0, 1, 0><<<dim3(4, 128), 256, 0, stream>>>(
      query_bf, 512, wq_t, 512, bq, nullptr, q_bf, nullptr, 512, 512, 0);
  k_gemm_bt<2, 1, 0><<<dim3(8, 128), 256, 0, stream>>>(
      target_bf, 512, wkv_t, 512, bk, bv, k_bf, v_t, 512, 512, 0);

  // 3) per-batch attention
  for (int b = 0; b < 4; ++b) {
    const unsigned short* qb  = q_bf + (size_t)b * 4096 * 512;
    const unsigned short* kb  = k_bf + (size_t)b * 4096 * 512;
    const unsigned short* vtb = v_t  + (size_t)b * 512 * 4096;
    unsigned short* ctxb = ctx + (size_t)b * 4096 * 512;

    // E = exp(Q K^T) (bf16, LDS-staged coalesced stores) + row-sum partials
    k_gemm_bt<3, 0, 0><<<dim3(32, 32), 256, 0, stream>>>(
        qb, 512, kb, 512, nullptr, nullptr, Sbuf, lsumPart, 4096, 512, 0);
    k_invl<<<16, 256, 0, stream>>>(lsumPart, invl);
    // partial = E @ V  (split-K x4, f32 partials)
    k_gemm_bt<1, 0, 1><<<dim3(4, 32, 4), 256, 0, stream>>>(
        Sbuf, 4096, vtb, 4096, nullptr, nullptr, part, nullptr, 512, 1024, 4096 * 512);
    // ctx = bf16((sum of partials) * invl)
    k_reduce_ks<4><<<2048, 256, 0, stream>>>(part, invl, ctxb);
  }

  // 4) output projection (f32 out, bias)
  k_gemm_bt<1, 1, 0><<<dim3(4, 128), 256, 0, stream>>>(
      ctx, 512, wo_t, 512, bo, nullptr, out, nullptr, 512, 512, 0);
}

// Round 8
// 499.128 us; speedup vs baseline: 1.1313x; 1.1313x over previous
//
#include <hip/hip_runtime.h>
#include <hip/hip_bf16.h>
#include <stdint.h>

#define AS1 __attribute__((address_space(1)))
#define AS3 __attribute__((address_space(3)))

typedef float f32x4 __attribute__((ext_vector_type(4)));
typedef __bf16 bf16x8 __attribute__((ext_vector_type(8)));

static __device__ __forceinline__ unsigned short f2bf(float f) {
  unsigned u = __float_as_uint(f);
  u += 0x7fff + ((u >> 16) & 1);   // RNE
  return (unsigned short)(u >> 16);
}

// ---------------- conversion kernels ----------------

__global__ __launch_bounds__(256) void k_f32_to_bf16(const float* __restrict__ in,
                                                     unsigned short* __restrict__ out, int n4) {
  int i = blockIdx.x * 256 + threadIdx.x;
  if (i >= n4) return;
  float4 v = reinterpret_cast<const float4*>(in)[i];
  ushort4 o;
  o.x = f2bf(v.x); o.y = f2bf(v.y); o.z = f2bf(v.z); o.w = f2bf(v.w);
  reinterpret_cast<ushort4*>(out)[i] = o;
}

// transpose + convert the four 512x512 weights: out[n*512+k] = bf16(w[k*512+n])
__global__ __launch_bounds__(256) void k_wtrans(const float* __restrict__ w0, const float* __restrict__ w1,
                                                const float* __restrict__ w2, const float* __restrict__ w3,
                                                unsigned short* __restrict__ o0, unsigned short* __restrict__ o1,
                                                unsigned short* __restrict__ o2, unsigned short* __restrict__ o3) {
  const float* w; unsigned short* o;
  switch (blockIdx.y) {
    case 0: w = w0; o = o0; break;
    case 1: w = w1; o = o1; break;
    case 2: w = w2; o = o2; break;
    default: w = w3; o = o3; break;
  }
  int idx = blockIdx.x * 256 + threadIdx.x;   // 0..262143
  int kk = idx >> 9;
  int n  = idx & 511;
  o[n * 512 + kk] = f2bf(w[idx]);
}

// ---------------- GEMM: C[M,N] = A[M,K] * Bt[N,K]^T (+bias) ----------------
// m97 structure: 128x128 tile, BK=32, 4 waves, global_load_lds width 16,
// mfma_f32_16x16x32_bf16. C frag layout col=lane&15, row=(lane>>4)*4+reg.
// NO XCD swizzle: R3 vs R5 budget analysis shows the swizzle cost ~+50 us on
// the S-GEMM (28 -> 78 us) while neutral elsewhere (all data L2/L3-fit).
// EPI: 0 = bf16 out
//      1 = f32 out (also split-K partials)
//      2 = dual KV: cols 0-511 -> bf16 K ; cols 512-1023 -> V^T scatter
//      3 = bf16(exp(v)) out + per-(block,column-half) row-sum partials to
//          Cout2[bx*2 + (wave&1)][4096]  (race-free slots)
// SPLITK: bz picks a kLen K-chunk, f32 partial at CoutF + bz*partStride.

template<int EPI, int HAS_BIAS, int SPLITK>
__global__ __launch_bounds__(256) void k_gemm_bt(
    const unsigned short* __restrict__ A, int lda,
    const unsigned short* __restrict__ Bt, int ldb,
    const float* __restrict__ bias, const float* __restrict__ bias2,
    void* __restrict__ Cout, void* __restrict__ Cout2,
    int ldc, int kLen, int partStride)
{
  __shared__ __align__(16) unsigned short sA[128 * 32];
  __shared__ __align__(16) unsigned short sB[128 * 32];

  const int bx = blockIdx.x;
  const int by = blockIdx.y;
  const int bz = blockIdx.z;

  float* CoutF = (float*)Cout;
  if (SPLITK) {
    A  += (size_t)bz * kLen;
    Bt += (size_t)bz * kLen;
    CoutF += (size_t)bz * partStride;
  }

  const int tid = threadIdx.x;
  const int tileM = by * 128;
  const int tileN = bx * 128;
  const unsigned short* Ab = A + (size_t)tileM * lda;
  const unsigned short* Bb = Bt + (size_t)tileN * ldb;

  f32x4 acc[4][4];
#pragma unroll
  for (int m = 0; m < 4; ++m)
#pragma unroll
    for (int n = 0; n < 4; ++n)
      acc[m][n] = (f32x4){0.f, 0.f, 0.f, 0.f};

  const int lane = tid & 63;
  const int w = tid >> 6;
  const int wr = (w >> 1) * 64;
  const int wc = (w & 1) * 64;
  const int fr = lane & 15;
  const int fk = (lane >> 4) * 8;

  for (int k0 = 0; k0 < kLen; k0 += 32) {
    __syncthreads();
#pragma unroll
    for (int i = 0; i < 2; ++i) {
      int c = tid + i * 256;         // 0..511 (16B chunks)
      int r = c >> 2;
      int cb = (c & 3) * 8;
      __builtin_amdgcn_global_load_lds((const AS1 void*)(Ab + (size_t)r * lda + k0 + cb),
                                       (AS3 void*)(&sA[c * 8]), 16, 0, 0);
      __builtin_amdgcn_global_load_lds((const AS1 void*)(Bb + (size_t)r * ldb + k0 + cb),
                                       (AS3 void*)(&sB[c * 8]), 16, 0, 0);
    }
    __syncthreads();

    bf16x8 af[4], bfr[4];
#pragma unroll
    for (int m = 0; m < 4; ++m)
      af[m] = *reinterpret_cast<const bf16x8*>(&sA[(wr + m * 16 + fr) * 32 + fk]);
#pragma unroll
    for (int n = 0; n < 4; ++n)
      bfr[n] = *reinterpret_cast<const bf16x8*>(&sB[(wc + n * 16 + fr) * 32 + fk]);
#pragma unroll
    for (int m = 0; m < 4; ++m)
#pragma unroll
      for (int n = 0; n < 4; ++n)
        acc[m][n] = __builtin_amdgcn_mfma_f32_16x16x32_bf16(af[m], bfr[n], acc[m][n], 0, 0, 0);
  }

  const int col4 = lane & 15;
  const int rw4 = (lane >> 4) * 4;

  if (EPI == 3) {
    // m-outer / n-inner: one scalar row-sum per (m,j), reduced immediately
    float* lsumPart = (float*)Cout2;
    const int slot = bx * 2 + (w & 1);
#pragma unroll
    for (int m = 0; m < 4; ++m) {
#pragma unroll
      for (int j = 0; j < 4; ++j) {
        const int gr = tileM + wr + m * 16 + rw4 + j;
        float rsum = 0.f;
#pragma unroll
        for (int n = 0; n < 4; ++n) {
          const int gc = tileN + wc + n * 16 + col4;
          float ev = __expf(acc[m][n][j]);
          ((unsigned short*)Cout)[(size_t)gr * ldc + gc] = f2bf(ev);
          rsum += ev;
        }
        rsum += __shfl_xor(rsum, 1); rsum += __shfl_xor(rsum, 2);
        rsum += __shfl_xor(rsum, 4); rsum += __shfl_xor(rsum, 8);
        if (col4 == 0) lsumPart[(size_t)slot * 4096 + gr] = rsum;
      }
    }
  } else {
#pragma unroll
    for (int n = 0; n < 4; ++n) {
      const int gc = tileN + wc + n * 16 + col4;
      float bval = 0.f;
      if (HAS_BIAS) bval = (EPI == 2) ? (gc < 512 ? bias[gc] : bias2[gc - 512]) : bias[gc];
#pragma unroll
      for (int m = 0; m < 4; ++m) {
        const int gr0 = tileM + wr + m * 16 + rw4;
#pragma unroll
        for (int j = 0; j < 4; ++j) {
          const int gr = gr0 + j;
          float v = acc[m][n][j] + bval;
          if (EPI == 1) {
            CoutF[(size_t)gr * ldc + gc] = v;
          } else if (EPI == 0) {
            ((unsigned short*)Cout)[(size_t)gr * ldc + gc] = f2bf(v);
          } else {  // EPI == 2: dual K | V^T
            if (gc < 512) {
              ((unsigned short*)Cout)[(size_t)gr * 512 + gc] = f2bf(v);
            } else {
              ((unsigned short*)Cout2)[((size_t)(gr >> 12)) * 2097152u
                                       + (size_t)(gc - 512) * 4096u
                                       + (size_t)(gr & 4095)] = f2bf(v);
            }
          }
        }
      }
    }
  }
}

// ---------------- invl[row] = 1 / sum_slot lsumPart[slot][row] ----------------

__global__ __launch_bounds__(256) void k_invl(const float* __restrict__ lsumPart,
                                              float* __restrict__ invl) {
  const int row = blockIdx.x * 256 + threadIdx.x;   // 4096 rows, 16 blocks
  float s = 0.f;
#pragma unroll
  for (int i = 0; i < 64; ++i) s += lsumPart[(size_t)i * 4096 + row];
  invl[row] = 1.0f / s;
}

// ------- split-K reduce + softmax normalization: ctx = bf16(sum * invl) ------

template<int NS>
__global__ __launch_bounds__(256) void k_reduce_ks(const float* __restrict__ part,
                                                   const float* __restrict__ invl,
                                                   unsigned short* __restrict__ out) {
  const int i = blockIdx.x * 256 + threadIdx.x;       // float4 index, 524288 total
  const float4* p = reinterpret_cast<const float4*>(part);
  float sx = 0.f, sy = 0.f, sz = 0.f, sw = 0.f;
#pragma unroll
  for (int z = 0; z < NS; ++z) {
    float4 a = p[i + (size_t)z * 524288];
    sx += a.x; sy += a.y; sz += a.z; sw += a.w;
  }
  const float iv = invl[i >> 7];                      // 128 float4 per 512-col row
  ushort4 o;
  o.x = f2bf(sx * iv); o.y = f2bf(sy * iv);
  o.z = f2bf(sz * iv); o.w = f2bf(sw * iv);
  reinterpret_cast<ushort4*>(out)[i] = o;
}

// ---------------- launch ----------------

extern "C" void kernel_launch(void* const* d_in, const int* in_sizes, int n_in,
                              void* d_out, int out_size, void* d_ws, size_t ws_size,
                              hipStream_t stream) {
  const float* query  = (const float*)d_in[0];
  const float* target = (const float*)d_in[1];
  const float* wq = (const float*)d_in[2];
  const float* bq = (const float*)d_in[3];
  const float* wk = (const float*)d_in[4];
  const float* bk = (const float*)d_in[5];
  const float* wv = (const float*)d_in[6];
  const float* bv = (const float*)d_in[7];
  const float* wo = (const float*)d_in[8];
  const float* bo = (const float*)d_in[9];
  float* out = (float*)d_out;

  const size_t SZ_BF = (size_t)16384 * 512 * 2;       // 16 MB

  char* ws = (char*)d_ws;
  size_t off = 0;
  unsigned short* query_bf  = (unsigned short*)(ws + off); off += SZ_BF;
  unsigned short* target_bf = (unsigned short*)(ws + off); off += SZ_BF;
  unsigned short* q_bf = (unsigned short*)(ws + off); off += SZ_BF;
  unsigned short* k_bf = (unsigned short*)(ws + off); off += SZ_BF;
  unsigned short* v_t  = (unsigned short*)(ws + off); off += SZ_BF;   // [B][512][4096]
  unsigned short* ctx  = (unsigned short*)(ws + off); off += SZ_BF;
  unsigned short* wq_t  = (unsigned short*)(ws + off); off += 512 * 512 * 2;
  unsigned short* wkv_t = (unsigned short*)(ws + off); off += 2 * 512 * 512 * 2;
  unsigned short* wo_t  = (unsigned short*)(ws + off); off += 512 * 512 * 2;
  unsigned short* Sbuf  = (unsigned short*)(ws + off); off += (size_t)4096 * 4096 * 2;  // 32 MB
  float* lsumPart = (float*)(ws + off); off += (size_t)64 * 4096 * 4;                   // 1 MB
  float* invl = (float*)(ws + off); off += 4096 * sizeof(float);
  (void)ws_size;

  // split-K partial buffer (4 x 4096x512 f32 = 32 MB): aliases query_bf/target_bf,
  // which are dead after the projection GEMMs complete (stream-ordered).
  float* part = (float*)ws;

  // 1) inputs -> bf16; weights -> bf16 transposed ([N][K])
  k_f32_to_bf16<<<8192, 256, 0, stream>>>(query,  query_bf,  2097152);
  k_f32_to_bf16<<<8192, 256, 0, stream>>>(target, target_bf, 2097152);
  k_wtrans<<<dim3(1024, 4), 256, 0, stream>>>(wq, wk, wv, wo,
                                              wq_t, wkv_t, wkv_t + 512 * 512, wo_t);

  // 2) projections  (M=16384, K=512)
  k_gemm_bt<0, 1, 0><<<dim3(4, 128), 256, 0, stream>>>(
      query_bf, 512, wq_t, 512, bq, nullptr, q_bf, nullptr, 512, 512, 0);
  k_gemm_bt<2, 1, 0><<<dim3(8, 128), 256, 0, stream>>>(
      target_bf, 512, wkv_t, 512, bk, bv, k_bf, v_t, 512, 512, 0);

  // 3) per-batch attention
  for (int b = 0; b < 4; ++b) {
    const unsigned short* qb  = q_bf + (size_t)b * 4096 * 512;
    const unsigned short* kb  = k_bf + (size_t)b * 4096 * 512;
    const unsigned short* vtb = v_t  + (size_t)b * 512 * 4096;
    unsigned short* ctxb = ctx + (size_t)b * 4096 * 512;

    // E = exp(Q K^T) (bf16) + per-(tile,half) row-sum partials
    k_gemm_bt<3, 0, 0><<<dim3(32, 32), 256, 0, stream>>>(
        qb, 512, kb, 512, nullptr, nullptr, Sbuf, lsumPart, 4096, 512, 0);
    k_invl<<<16, 256, 0, stream>>>(lsumPart, invl);
    // partial = E @ V  (split-K x4, f32 partials)
    k_gemm_bt<1, 0, 1><<<dim3(4, 32, 4), 256, 0, stream>>>(
        Sbuf, 4096, vtb, 4096, nullptr, nullptr, part, nullptr, 512, 1024, 4096 * 512);
    // ctx = bf16((sum of partials) * invl)
    k_reduce_ks<4><<<2048, 256, 0, stream>>>(part, invl, ctxb);
  }

  // 4) output projection (f32 out, bias)
  k_gemm_bt<1, 1, 0><<<dim3(4, 128), 256, 0, stream>>>(
      ctx, 512, wo_t, 512, bo, nullptr, out, nullptr, 512, 512, 0);
}

// Round 9
// 399.127 us; speedup vs baseline: 1.4148x; 1.2506x over previous
//
#include <hip/hip_runtime.h>
#include <hip/hip_bf16.h>
#include <stdint.h>

#define AS1 __attribute__((address_space(1)))
#define AS3 __attribute__((address_space(3)))

typedef float f32x4 __attribute__((ext_vector_type(4)));
typedef __bf16 bf16x8 __attribute__((ext_vector_type(8)));

static __device__ __forceinline__ unsigned short f2bf(float f) {
  unsigned u = __float_as_uint(f);
  u += 0x7fff + ((u >> 16) & 1);   // RNE
  return (unsigned short)(u >> 16);
}
static __device__ __forceinline__ float bf2f_lo(unsigned u) { return __uint_as_float(u << 16); }
static __device__ __forceinline__ float bf2f_hi(unsigned u) { return __uint_as_float(u & 0xffff0000u); }

// ---------------- conversion kernels ----------------

__global__ __launch_bounds__(256) void k_f32_to_bf16(const float* __restrict__ in,
                                                     unsigned short* __restrict__ out, int n4) {
  int i = blockIdx.x * 256 + threadIdx.x;
  if (i >= n4) return;
  float4 v = reinterpret_cast<const float4*>(in)[i];
  ushort4 o;
  o.x = f2bf(v.x); o.y = f2bf(v.y); o.z = f2bf(v.z); o.w = f2bf(v.w);
  reinterpret_cast<ushort4*>(out)[i] = o;
}

// transpose + convert the four 512x512 weights: out[n*512+k] = bf16(w[k*512+n])
__global__ __launch_bounds__(256) void k_wtrans(const float* __restrict__ w0, const float* __restrict__ w1,
                                                const float* __restrict__ w2, const float* __restrict__ w3,
                                                unsigned short* __restrict__ o0, unsigned short* __restrict__ o1,
                                                unsigned short* __restrict__ o2, unsigned short* __restrict__ o3) {
  const float* w; unsigned short* o;
  switch (blockIdx.y) {
    case 0: w = w0; o = o0; break;
    case 1: w = w1; o = o1; break;
    case 2: w = w2; o = o2; break;
    default: w = w3; o = o3; break;
  }
  int idx = blockIdx.x * 256 + threadIdx.x;   // 0..262143
  int kk = idx >> 9;
  int n  = idx & 511;
  o[n * 512 + kk] = f2bf(w[idx]);
}

// ---------------- shared GEMM body: C[M,N] = A[M,K] * Bt[N,K]^T (+bias) -----
// m97 structure: 128x128 tile, BK=32, 4 waves, global_load_lds width 16,
// mfma_f32_16x16x32_bf16. C frag layout col=lane&15, row=(lane>>4)*4+reg.
// No XCD swizzle. EPI: 0=bf16+bias  1=f32(+bias if HAS_BIAS)  2=dual K|V^T
// 3=bf16(exp(v)) only (R3 form — row-sum handled by separate k_rowsum).
// SPLITK: bz picks a kLen K-chunk, f32 partial at CoutF + bz*partStride.

template<int EPI, int HAS_BIAS, int SPLITK>
static __device__ __forceinline__ void gemm_body(
    const unsigned short* __restrict__ A, int lda,
    const unsigned short* __restrict__ Bt, int ldb,
    const float* __restrict__ bias, const float* __restrict__ bias2,
    void* __restrict__ Cout, void* __restrict__ Cout2,
    int ldc, int kLen, int partStride)
{
  __shared__ __align__(16) unsigned short sA[128 * 32];
  __shared__ __align__(16) unsigned short sB[128 * 32];

  const int bx = blockIdx.x;
  const int by = blockIdx.y;
  const int bz = blockIdx.z;

  float* CoutF = (float*)Cout;
  if (SPLITK) {
    A  += (size_t)bz * kLen;
    Bt += (size_t)bz * kLen;
    CoutF += (size_t)bz * partStride;
  }

  const int tid = threadIdx.x;
  const int tileM = by * 128;
  const int tileN = bx * 128;
  const unsigned short* Ab = A + (size_t)tileM * lda;
  const unsigned short* Bb = Bt + (size_t)tileN * ldb;

  f32x4 acc[4][4];
#pragma unroll
  for (int m = 0; m < 4; ++m)
#pragma unroll
    for (int n = 0; n < 4; ++n)
      acc[m][n] = (f32x4){0.f, 0.f, 0.f, 0.f};

  const int lane = tid & 63;
  const int w = tid >> 6;
  const int wr = (w >> 1) * 64;
  const int wc = (w & 1) * 64;
  const int fr = lane & 15;
  const int fk = (lane >> 4) * 8;

  for (int k0 = 0; k0 < kLen; k0 += 32) {
    __syncthreads();
#pragma unroll
    for (int i = 0; i < 2; ++i) {
      int c = tid + i * 256;         // 0..511 (16B chunks)
      int r = c >> 2;
      int cb = (c & 3) * 8;
      __builtin_amdgcn_global_load_lds((const AS1 void*)(Ab + (size_t)r * lda + k0 + cb),
                                       (AS3 void*)(&sA[c * 8]), 16, 0, 0);
      __builtin_amdgcn_global_load_lds((const AS1 void*)(Bb + (size_t)r * ldb + k0 + cb),
                                       (AS3 void*)(&sB[c * 8]), 16, 0, 0);
    }
    __syncthreads();

    bf16x8 af[4], bfr[4];
#pragma unroll
    for (int m = 0; m < 4; ++m)
      af[m] = *reinterpret_cast<const bf16x8*>(&sA[(wr + m * 16 + fr) * 32 + fk]);
#pragma unroll
    for (int n = 0; n < 4; ++n)
      bfr[n] = *reinterpret_cast<const bf16x8*>(&sB[(wc + n * 16 + fr) * 32 + fk]);
#pragma unroll
    for (int m = 0; m < 4; ++m)
#pragma unroll
      for (int n = 0; n < 4; ++n)
        acc[m][n] = __builtin_amdgcn_mfma_f32_16x16x32_bf16(af[m], bfr[n], acc[m][n], 0, 0, 0);
  }

  const int col4 = lane & 15;
  const int rw4 = (lane >> 4) * 4;
#pragma unroll
  for (int n = 0; n < 4; ++n) {
    const int gc = tileN + wc + n * 16 + col4;
    float bval = 0.f;
    if (HAS_BIAS) bval = (EPI == 2) ? (gc < 512 ? bias[gc] : bias2[gc - 512]) : bias[gc];
#pragma unroll
    for (int m = 0; m < 4; ++m) {
      const int gr0 = tileM + wr + m * 16 + rw4;
#pragma unroll
      for (int j = 0; j < 4; ++j) {
        const int gr = gr0 + j;
        float v = acc[m][n][j] + bval;
        if (EPI == 1) {
          CoutF[(size_t)gr * ldc + gc] = v;
        } else if (EPI == 0) {
          ((unsigned short*)Cout)[(size_t)gr * ldc + gc] = f2bf(v);
        } else if (EPI == 3) {
          ((unsigned short*)Cout)[(size_t)gr * ldc + gc] = f2bf(__expf(v));
        } else {  // EPI == 2: dual K | V^T
          if (gc < 512) {
            ((unsigned short*)Cout)[(size_t)gr * 512 + gc] = f2bf(v);
          } else {
            ((unsigned short*)Cout2)[((size_t)(gr >> 12)) * 2097152u
                                     + (size_t)(gc - 512) * 4096u
                                     + (size_t)(gr & 4095)] = f2bf(v);
          }
        }
      }
    }
  }
}

// ------------- named kernel wrappers (distinct rocprof Kernel_Name) ---------

__global__ __launch_bounds__(256) void k_proj_q(
    const unsigned short* __restrict__ A, const unsigned short* __restrict__ Bt,
    const float* __restrict__ bias, unsigned short* __restrict__ C) {
  gemm_body<0, 1, 0>(A, 512, Bt, 512, bias, nullptr, C, nullptr, 512, 512, 0);
}

__global__ __launch_bounds__(256) void k_proj_kv(
    const unsigned short* __restrict__ A, const unsigned short* __restrict__ Bt,
    const float* __restrict__ biask, const float* __restrict__ biasv,
    unsigned short* __restrict__ K, unsigned short* __restrict__ Vt) {
  gemm_body<2, 1, 0>(A, 512, Bt, 512, biask, biasv, K, Vt, 512, 512, 0);
}

__global__ __launch_bounds__(256) void k_sexp(
    const unsigned short* __restrict__ Q, const unsigned short* __restrict__ K,
    unsigned short* __restrict__ E) {
  gemm_body<3, 0, 0>(Q, 512, K, 512, nullptr, nullptr, E, nullptr, 4096, 512, 0);
}

__global__ __launch_bounds__(256) void k_pv(
    const unsigned short* __restrict__ E, const unsigned short* __restrict__ Vt,
    float* __restrict__ part) {
  gemm_body<1, 0, 1>(E, 4096, Vt, 4096, nullptr, nullptr, part, nullptr, 512, 1024, 4096 * 512);
}

__global__ __launch_bounds__(256) void k_oproj(
    const unsigned short* __restrict__ A, const unsigned short* __restrict__ Bt,
    const float* __restrict__ bias, float* __restrict__ C) {
  gemm_body<1, 1, 0>(A, 512, Bt, 512, bias, nullptr, C, nullptr, 512, 512, 0);
}

// ---------------- row sum of E = exp(S): invl[row] = 1 / sum (R3 form) ------

__global__ __launch_bounds__(256) void k_rowsum(const unsigned short* __restrict__ E,
                                                float* __restrict__ invl) {
  const int row = blockIdx.x;
  const uint4* p = reinterpret_cast<const uint4*>(E + (size_t)row * 4096);
  const int tid = threadIdx.x;
  float s = 0.f;
#pragma unroll
  for (int i = 0; i < 2; ++i) {
    uint4 u = p[tid + i * 256];
    s += bf2f_lo(u.x) + bf2f_hi(u.x) + bf2f_lo(u.y) + bf2f_hi(u.y)
       + bf2f_lo(u.z) + bf2f_hi(u.z) + bf2f_lo(u.w) + bf2f_hi(u.w);
  }
#pragma unroll
  for (int off = 32; off >= 1; off >>= 1) s += __shfl_xor(s, off);
  __shared__ float reds[4];
  const int wv = tid >> 6, ln = tid & 63;
  if (ln == 0) reds[wv] = s;
  __syncthreads();
  if (tid == 0) {
    float t = reds[0] + reds[1] + reds[2] + reds[3];
    invl[row] = 1.0f / t;
  }
}

// ------- split-K reduce + softmax normalization: ctx = bf16(sum * invl) ------

__global__ __launch_bounds__(256) void k_reduce_ks(const float* __restrict__ part,
                                                   const float* __restrict__ invl,
                                                   unsigned short* __restrict__ out) {
  const int i = blockIdx.x * 256 + threadIdx.x;       // float4 index, 524288 total
  const float4* p = reinterpret_cast<const float4*>(part);
  float4 a = p[i];
  float4 b = p[i + 524288];
  float4 c = p[i + 2 * 524288];
  float4 d = p[i + 3 * 524288];
  const float iv = invl[i >> 7];                      // 128 float4 per 512-col row
  float4 s;
  s.x = ((a.x + b.x) + (c.x + d.x)) * iv;
  s.y = ((a.y + b.y) + (c.y + d.y)) * iv;
  s.z = ((a.z + b.z) + (c.z + d.z)) * iv;
  s.w = ((a.w + b.w) + (c.w + d.w)) * iv;
  ushort4 o;
  o.x = f2bf(s.x); o.y = f2bf(s.y); o.z = f2bf(s.z); o.w = f2bf(s.w);
  reinterpret_cast<ushort4*>(out)[i] = o;
}

// ---------------- launch ----------------

extern "C" void kernel_launch(void* const* d_in, const int* in_sizes, int n_in,
                              void* d_out, int out_size, void* d_ws, size_t ws_size,
                              hipStream_t stream) {
  const float* query  = (const float*)d_in[0];
  const float* target = (const float*)d_in[1];
  const float* wq = (const float*)d_in[2];
  const float* bq = (const float*)d_in[3];
  const float* wk = (const float*)d_in[4];
  const float* bk = (const float*)d_in[5];
  const float* wv = (const float*)d_in[6];
  const float* bv = (const float*)d_in[7];
  const float* wo = (const float*)d_in[8];
  const float* bo = (const float*)d_in[9];
  float* out = (float*)d_out;

  const size_t SZ_BF = (size_t)16384 * 512 * 2;       // 16 MB

  char* ws = (char*)d_ws;
  size_t off = 0;
  unsigned short* query_bf  = (unsigned short*)(ws + off); off += SZ_BF;
  unsigned short* target_bf = (unsigned short*)(ws + off); off += SZ_BF;
  unsigned short* q_bf = (unsigned short*)(ws + off); off += SZ_BF;
  unsigned short* k_bf = (unsigned short*)(ws + off); off += SZ_BF;
  unsigned short* v_t  = (unsigned short*)(ws + off); off += SZ_BF;   // [B][512][4096]
  unsigned short* ctx  = (unsigned short*)(ws + off); off += SZ_BF;
  unsigned short* wq_t  = (unsigned short*)(ws + off); off += 512 * 512 * 2;
  unsigned short* wkv_t = (unsigned short*)(ws + off); off += 2 * 512 * 512 * 2;
  unsigned short* wo_t  = (unsigned short*)(ws + off); off += 512 * 512 * 2;
  unsigned short* Sbuf  = (unsigned short*)(ws + off); off += (size_t)4096 * 4096 * 2;  // 32 MB
  float* invl = (float*)(ws + off); off += 4096 * sizeof(float);
  (void)ws_size;

  // split-K partial buffer (4 x 4096x512 f32 = 32 MB): aliases query_bf/target_bf,
  // which are dead after the projection GEMMs complete (stream-ordered).
  float* part = (float*)ws;

  // 1) inputs -> bf16; weights -> bf16 transposed ([N][K])
  k_f32_to_bf16<<<8192, 256, 0, stream>>>(query,  query_bf,  2097152);
  k_f32_to_bf16<<<8192, 256, 0, stream>>>(target, target_bf, 2097152);
  k_wtrans<<<dim3(1024, 4), 256, 0, stream>>>(wq, wk, wv, wo,
                                              wq_t, wkv_t, wkv_t + 512 * 512, wo_t);

  // 2) projections  (M=16384, K=512)
  k_proj_q<<<dim3(4, 128), 256, 0, stream>>>(query_bf, wq_t, bq, q_bf);
  k_proj_kv<<<dim3(8, 128), 256, 0, stream>>>(target_bf, wkv_t, bk, bv, k_bf, v_t);

  // 3) per-batch attention
  for (int b = 0; b < 4; ++b) {
    const unsigned short* qb  = q_bf + (size_t)b * 4096 * 512;
    const unsigned short* kb  = k_bf + (size_t)b * 4096 * 512;
    const unsigned short* vtb = v_t  + (size_t)b * 512 * 4096;
    unsigned short* ctxb = ctx + (size_t)b * 4096 * 512;

    // E = exp(Q K^T)  (bf16, plain epilogue — R3 form)
    k_sexp<<<dim3(32, 32), 256, 0, stream>>>(qb, kb, Sbuf);
    // invl = 1 / row-sum(E)
    k_rowsum<<<4096, 256, 0, stream>>>(Sbuf, invl);
    // partial = E @ V  (split-K x4, f32 partials)
    k_pv<<<dim3(4, 32, 4), 256, 0, stream>>>(Sbuf, vtb, part);
    // ctx = bf16((sum of partials) * invl)
    k_reduce_ks<<<2048, 256, 0, stream>>>(part, invl, ctxb);
  }

  // 4) output projection (f32 out, bias)
  k_oproj<<<dim3(4, 128), 256, 0, stream>>>(ctx, wo_t, bo, out);
}

// Round 10
// 391.384 us; speedup vs baseline: 1.4427x; 1.0198x over previous
//
#include <hip/hip_runtime.h>
#include <hip/hip_bf16.h>
#include <stdint.h>

#define AS1 __attribute__((address_space(1)))
#define AS3 __attribute__((address_space(3)))

typedef float f32x4 __attribute__((ext_vector_type(4)));
typedef __bf16 bf16x8 __attribute__((ext_vector_type(8)));

static __device__ __forceinline__ unsigned short f2bf(float f) {
  unsigned u = __float_as_uint(f);
  u += 0x7fff + ((u >> 16) & 1);   // RNE
  return (unsigned short)(u >> 16);
}
static __device__ __forceinline__ float bf2f_lo(unsigned u) { return __uint_as_float(u << 16); }
static __device__ __forceinline__ float bf2f_hi(unsigned u) { return __uint_as_float(u & 0xffff0000u); }

// ---------------- conversion kernels ----------------

__global__ __launch_bounds__(256) void k_f32_to_bf16(const float* __restrict__ in,
                                                     unsigned short* __restrict__ out, int n4) {
  int i = blockIdx.x * 256 + threadIdx.x;
  if (i >= n4) return;
  float4 v = reinterpret_cast<const float4*>(in)[i];
  ushort4 o;
  o.x = f2bf(v.x); o.y = f2bf(v.y); o.z = f2bf(v.z); o.w = f2bf(v.w);
  reinterpret_cast<ushort4*>(out)[i] = o;
}

// transpose + convert the four 512x512 weights: out[n*512+k] = bf16(w[k*512+n])
__global__ __launch_bounds__(256) void k_wtrans(const float* __restrict__ w0, const float* __restrict__ w1,
                                                const float* __restrict__ w2, const float* __restrict__ w3,
                                                unsigned short* __restrict__ o0, unsigned short* __restrict__ o1,
                                                unsigned short* __restrict__ o2, unsigned short* __restrict__ o3) {
  const float* w; unsigned short* o;
  switch (blockIdx.y) {
    case 0: w = w0; o = o0; break;
    case 1: w = w1; o = o1; break;
    case 2: w = w2; o = o2; break;
    default: w = w3; o = o3; break;
  }
  int idx = blockIdx.x * 256 + threadIdx.x;   // 0..262143
  int kk = idx >> 9;
  int n  = idx & 511;
  o[n * 512 + kk] = f2bf(w[idx]);
}

// ---- V transpose: v_row[16384][512] -> v_t[b][512][4096], 64x64 LDS tiles ----

__global__ __launch_bounds__(256) void k_vtrans(const unsigned short* __restrict__ vr,
                                                unsigned short* __restrict__ vt) {
  __shared__ unsigned short lds[64 * 66];    // pad 66: bank-friendly
  const int tid = threadIdx.x;
  const int d0 = blockIdx.x * 64;            // 0..448
  const int s0 = blockIdx.y * 64;            // 0..16320 (tile within one batch)
  const int r = tid >> 4;                    // 0..15
  const int c4 = (tid & 15) * 4;             // 0,4,...,60
#pragma unroll
  for (int i = 0; i < 4; ++i) {
    const int row = i * 16 + r;              // s-offset in tile
    ushort4 v = *reinterpret_cast<const ushort4*>(&vr[(size_t)(s0 + row) * 512 + d0 + c4]);
    lds[row * 66 + c4 + 0] = v.x;
    lds[row * 66 + c4 + 1] = v.y;
    lds[row * 66 + c4 + 2] = v.z;
    lds[row * 66 + c4 + 3] = v.w;
  }
  __syncthreads();
  const int b = s0 >> 12;
  const int sin = s0 & 4095;
#pragma unroll
  for (int i = 0; i < 4; ++i) {
    const int drow = i * 16 + r;             // d-offset in tile
    ushort4 o;
    o.x = lds[(c4 + 0) * 66 + drow];
    o.y = lds[(c4 + 1) * 66 + drow];
    o.z = lds[(c4 + 2) * 66 + drow];
    o.w = lds[(c4 + 3) * 66 + drow];
    *reinterpret_cast<ushort4*>(&vt[(size_t)b * 2097152u + (size_t)(d0 + drow) * 4096u
                                    + sin + c4]) = o;
  }
}

// ---------------- shared GEMM body: C[M,N] = A[M,K] * Bt[N,K]^T (+bias) -----
// m97 structure: 128x128 tile, BK=32, 4 waves, global_load_lds width 16,
// mfma_f32_16x16x32_bf16. C frag layout col=lane&15, row=(lane>>4)*4+reg.
// No XCD swizzle. EPI: 0=bf16+bias  1=f32(+bias if HAS_BIAS)
// 2=dual KV, BOTH row-major (V transposed later by k_vtrans)
// 3=bf16(exp(v)) only (row-sum handled by separate k_rowsum).
// SPLITK: bz picks a kLen K-chunk, f32 partial at CoutF + bz*partStride.

template<int EPI, int HAS_BIAS, int SPLITK>
static __device__ __forceinline__ void gemm_body(
    const unsigned short* __restrict__ A, int lda,
    const unsigned short* __restrict__ Bt, int ldb,
    const float* __restrict__ bias, const float* __restrict__ bias2,
    void* __restrict__ Cout, void* __restrict__ Cout2,
    int ldc, int kLen, int partStride)
{
  __shared__ __align__(16) unsigned short sA[128 * 32];
  __shared__ __align__(16) unsigned short sB[128 * 32];

  const int bx = blockIdx.x;
  const int by = blockIdx.y;
  const int bz = blockIdx.z;

  float* CoutF = (float*)Cout;
  if (SPLITK) {
    A  += (size_t)bz * kLen;
    Bt += (size_t)bz * kLen;
    CoutF += (size_t)bz * partStride;
  }

  const int tid = threadIdx.x;
  const int tileM = by * 128;
  const int tileN = bx * 128;
  const unsigned short* Ab = A + (size_t)tileM * lda;
  const unsigned short* Bb = Bt + (size_t)tileN * ldb;

  f32x4 acc[4][4];
#pragma unroll
  for (int m = 0; m < 4; ++m)
#pragma unroll
    for (int n = 0; n < 4; ++n)
      acc[m][n] = (f32x4){0.f, 0.f, 0.f, 0.f};

  const int lane = tid & 63;
  const int w = tid >> 6;
  const int wr = (w >> 1) * 64;
  const int wc = (w & 1) * 64;
  const int fr = lane & 15;
  const int fk = (lane >> 4) * 8;

  for (int k0 = 0; k0 < kLen; k0 += 32) {
    __syncthreads();
#pragma unroll
    for (int i = 0; i < 2; ++i) {
      int c = tid + i * 256;         // 0..511 (16B chunks)
      int r = c >> 2;
      int cb = (c & 3) * 8;
      __builtin_amdgcn_global_load_lds((const AS1 void*)(Ab + (size_t)r * lda + k0 + cb),
                                       (AS3 void*)(&sA[c * 8]), 16, 0, 0);
      __builtin_amdgcn_global_load_lds((const AS1 void*)(Bb + (size_t)r * ldb + k0 + cb),
                                       (AS3 void*)(&sB[c * 8]), 16, 0, 0);
    }
    __syncthreads();

    bf16x8 af[4], bfr[4];
#pragma unroll
    for (int m = 0; m < 4; ++m)
      af[m] = *reinterpret_cast<const bf16x8*>(&sA[(wr + m * 16 + fr) * 32 + fk]);
#pragma unroll
    for (int n = 0; n < 4; ++n)
      bfr[n] = *reinterpret_cast<const bf16x8*>(&sB[(wc + n * 16 + fr) * 32 + fk]);
#pragma unroll
    for (int m = 0; m < 4; ++m)
#pragma unroll
      for (int n = 0; n < 4; ++n)
        acc[m][n] = __builtin_amdgcn_mfma_f32_16x16x32_bf16(af[m], bfr[n], acc[m][n], 0, 0, 0);
  }

  const int col4 = lane & 15;
  const int rw4 = (lane >> 4) * 4;
#pragma unroll
  for (int n = 0; n < 4; ++n) {
    const int gc = tileN + wc + n * 16 + col4;
    float bval = 0.f;
    if (HAS_BIAS) bval = (EPI == 2) ? (gc < 512 ? bias[gc] : bias2[gc - 512]) : bias[gc];
#pragma unroll
    for (int m = 0; m < 4; ++m) {
      const int gr0 = tileM + wr + m * 16 + rw4;
#pragma unroll
      for (int j = 0; j < 4; ++j) {
        const int gr = gr0 + j;
        float v = acc[m][n][j] + bval;
        if (EPI == 1) {
          CoutF[(size_t)gr * ldc + gc] = v;
        } else if (EPI == 0) {
          ((unsigned short*)Cout)[(size_t)gr * ldc + gc] = f2bf(v);
        } else if (EPI == 3) {
          ((unsigned short*)Cout)[(size_t)gr * ldc + gc] = f2bf(__expf(v));
        } else {  // EPI == 2: dual K | V, both row-major [16384][512]
          if (gc < 512) {
            ((unsigned short*)Cout)[(size_t)gr * 512 + gc] = f2bf(v);
          } else {
            ((unsigned short*)Cout2)[(size_t)gr * 512 + (gc - 512)] = f2bf(v);
          }
        }
      }
    }
  }
}

// ------------- named kernel wrappers (distinct rocprof Kernel_Name) ---------

__global__ __launch_bounds__(256) void k_proj_q(
    const unsigned short* __restrict__ A, const unsigned short* __restrict__ Bt,
    const float* __restrict__ bias, unsigned short* __restrict__ C) {
  gemm_body<0, 1, 0>(A, 512, Bt, 512, bias, nullptr, C, nullptr, 512, 512, 0);
}

__global__ __launch_bounds__(256) void k_proj_kv(
    const unsigned short* __restrict__ A, const unsigned short* __restrict__ Bt,
    const float* __restrict__ biask, const float* __restrict__ biasv,
    unsigned short* __restrict__ K, unsigned short* __restrict__ Vrow) {
  gemm_body<2, 1, 0>(A, 512, Bt, 512, biask, biasv, K, Vrow, 512, 512, 0);
}

__global__ __launch_bounds__(256) void k_sexp(
    const unsigned short* __restrict__ Q, const unsigned short* __restrict__ K,
    unsigned short* __restrict__ E) {
  gemm_body<3, 0, 0>(Q, 512, K, 512, nullptr, nullptr, E, nullptr, 4096, 512, 0);
}

__global__ __launch_bounds__(256) void k_pv(
    const unsigned short* __restrict__ E, const unsigned short* __restrict__ Vt,
    float* __restrict__ part) {
  gemm_body<1, 0, 1>(E, 4096, Vt, 4096, nullptr, nullptr, part, nullptr, 512, 1024, 4096 * 512);
}

__global__ __launch_bounds__(256) void k_oproj(
    const unsigned short* __restrict__ A, const unsigned short* __restrict__ Bt,
    const float* __restrict__ bias, float* __restrict__ C) {
  gemm_body<1, 1, 0>(A, 512, Bt, 512, bias, nullptr, C, nullptr, 512, 512, 0);
}

// ---------------- row sum of E = exp(S): invl[row] = 1 / sum ----------------

__global__ __launch_bounds__(256) void k_rowsum(const unsigned short* __restrict__ E,
                                                float* __restrict__ invl) {
  const int row = blockIdx.x;
  const uint4* p = reinterpret_cast<const uint4*>(E + (size_t)row * 4096);
  const int tid = threadIdx.x;
  float s = 0.f;
#pragma unroll
  for (int i = 0; i < 2; ++i) {
    uint4 u = p[tid + i * 256];
    s += bf2f_lo(u.x) + bf2f_hi(u.x) + bf2f_lo(u.y) + bf2f_hi(u.y)
       + bf2f_lo(u.z) + bf2f_hi(u.z) + bf2f_lo(u.w) + bf2f_hi(u.w);
  }
#pragma unroll
  for (int off = 32; off >= 1; off >>= 1) s += __shfl_xor(s, off);
  __shared__ float reds[4];
  const int wv = tid >> 6, ln = tid & 63;
  if (ln == 0) reds[wv] = s;
  __syncthreads();
  if (tid == 0) {
    float t = reds[0] + reds[1] + reds[2] + reds[3];
    invl[row] = 1.0f / t;
  }
}

// ------- split-K reduce + softmax normalization: ctx = bf16(sum * invl) ------

__global__ __launch_bounds__(256) void k_reduce_ks(const float* __restrict__ part,
                                                   const float* __restrict__ invl,
                                                   unsigned short* __restrict__ out) {
  const int i = blockIdx.x * 256 + threadIdx.x;       // float4 index, 524288 total
  const float4* p = reinterpret_cast<const float4*>(part);
  float4 a = p[i];
  float4 b = p[i + 524288];
  float4 c = p[i + 2 * 524288];
  float4 d = p[i + 3 * 524288];
  const float iv = invl[i >> 7];                      // 128 float4 per 512-col row
  float4 s;
  s.x = ((a.x + b.x) + (c.x + d.x)) * iv;
  s.y = ((a.y + b.y) + (c.y + d.y)) * iv;
  s.z = ((a.z + b.z) + (c.z + d.z)) * iv;
  s.w = ((a.w + b.w) + (c.w + d.w)) * iv;
  ushort4 o;
  o.x = f2bf(s.x); o.y = f2bf(s.y); o.z = f2bf(s.z); o.w = f2bf(s.w);
  reinterpret_cast<ushort4*>(out)[i] = o;
}

// ---------------- launch ----------------

extern "C" void kernel_launch(void* const* d_in, const int* in_sizes, int n_in,
                              void* d_out, int out_size, void* d_ws, size_t ws_size,
                              hipStream_t stream) {
  const float* query  = (const float*)d_in[0];
  const float* target = (const float*)d_in[1];
  const float* wq = (const float*)d_in[2];
  const float* bq = (const float*)d_in[3];
  const float* wk = (const float*)d_in[4];
  const float* bk = (const float*)d_in[5];
  const float* wv = (const float*)d_in[6];
  const float* bv = (const float*)d_in[7];
  const float* wo = (const float*)d_in[8];
  const float* bo = (const float*)d_in[9];
  float* out = (float*)d_out;

  const size_t SZ_BF = (size_t)16384 * 512 * 2;       // 16 MB

  char* ws = (char*)d_ws;
  size_t off = 0;
  unsigned short* query_bf  = (unsigned short*)(ws + off); off += SZ_BF;
  unsigned short* target_bf = (unsigned short*)(ws + off); off += SZ_BF;
  unsigned short* q_bf  = (unsigned short*)(ws + off); off += SZ_BF;
  unsigned short* k_bf  = (unsigned short*)(ws + off); off += SZ_BF;
  unsigned short* v_row = (unsigned short*)(ws + off); off += SZ_BF;  // [16384][512]
  unsigned short* v_t   = (unsigned short*)(ws + off); off += SZ_BF;  // [B][512][4096]
  unsigned short* ctx   = (unsigned short*)(ws + off); off += SZ_BF;
  unsigned short* wq_t  = (unsigned short*)(ws + off); off += 512 * 512 * 2;
  unsigned short* wkv_t = (unsigned short*)(ws + off); off += 2 * 512 * 512 * 2;
  unsigned short* wo_t  = (unsigned short*)(ws + off); off += 512 * 512 * 2;
  unsigned short* Sbuf  = (unsigned short*)(ws + off); off += (size_t)4096 * 4096 * 2;  // 32 MB
  float* invl = (float*)(ws + off); off += 4096 * sizeof(float);
  (void)ws_size;

  // split-K partial buffer (4 x 4096x512 f32 = 32 MB): aliases query_bf/target_bf,
  // which are dead after the projection GEMMs complete (stream-ordered).
  float* part = (float*)ws;

  // 1) inputs -> bf16; weights -> bf16 transposed ([N][K])
  k_f32_to_bf16<<<8192, 256, 0, stream>>>(query,  query_bf,  2097152);
  k_f32_to_bf16<<<8192, 256, 0, stream>>>(target, target_bf, 2097152);
  k_wtrans<<<dim3(1024, 4), 256, 0, stream>>>(wq, wk, wv, wo,
                                              wq_t, wkv_t, wkv_t + 512 * 512, wo_t);

  // 2) projections  (M=16384, K=512); V row-major, then tiled transpose
  k_proj_q<<<dim3(4, 128), 256, 0, stream>>>(query_bf, wq_t, bq, q_bf);
  k_proj_kv<<<dim3(8, 128), 256, 0, stream>>>(target_bf, wkv_t, bk, bv, k_bf, v_row);
  k_vtrans<<<dim3(8, 256), 256, 0, stream>>>(v_row, v_t);

  // 3) per-batch attention
  for (int b = 0; b < 4; ++b) {
    const unsigned short* qb  = q_bf + (size_t)b * 4096 * 512;
    const unsigned short* kb  = k_bf + (size_t)b * 4096 * 512;
    const unsigned short* vtb = v_t  + (size_t)b * 512 * 4096;
    unsigned short* ctxb = ctx + (size_t)b * 4096 * 512;

    // E = exp(Q K^T)  (bf16, plain epilogue)
    k_sexp<<<dim3(32, 32), 256, 0, stream>>>(qb, kb, Sbuf);
    // invl = 1 / row-sum(E)
    k_rowsum<<<4096, 256, 0, stream>>>(Sbuf, invl);
    // partial = E @ V  (split-K x4, f32 partials)
    k_pv<<<dim3(4, 32, 4), 256, 0, stream>>>(Sbuf, vtb, part);
    // ctx = bf16((sum of partials) * invl)
    k_reduce_ks<<<2048, 256, 0, stream>>>(part, invl, ctxb);
  }

  // 4) output projection (f32 out, bias)
  k_oproj<<<dim3(4, 128), 256, 0, stream>>>(ctx, wo_t, bo, out);
}

// Round 11
// 374.938 us; speedup vs baseline: 1.5060x; 1.0439x over previous
//
#include <hip/hip_runtime.h>
#include <hip/hip_bf16.h>
#include <stdint.h>

#define AS1 __attribute__((address_space(1)))
#define AS3 __attribute__((address_space(3)))

typedef float f32x4 __attribute__((ext_vector_type(4)));
typedef __bf16 bf16x8 __attribute__((ext_vector_type(8)));

static __device__ __forceinline__ unsigned short f2bf(float f) {
  unsigned u = __float_as_uint(f);
  u += 0x7fff + ((u >> 16) & 1);   // RNE
  return (unsigned short)(u >> 16);
}
static __device__ __forceinline__ float bf2f_lo(unsigned u) { return __uint_as_float(u << 16); }
static __device__ __forceinline__ float bf2f_hi(unsigned u) { return __uint_as_float(u & 0xffff0000u); }

// ---------------- conversion kernels ----------------

__global__ __launch_bounds__(256) void k_f32_to_bf16(const float* __restrict__ in,
                                                     unsigned short* __restrict__ out, int n4) {
  int i = blockIdx.x * 256 + threadIdx.x;
  if (i >= n4) return;
  float4 v = reinterpret_cast<const float4*>(in)[i];
  ushort4 o;
  o.x = f2bf(v.x); o.y = f2bf(v.y); o.z = f2bf(v.z); o.w = f2bf(v.w);
  reinterpret_cast<ushort4*>(out)[i] = o;
}

// transpose + convert the four 512x512 weights: out[n*512+k] = bf16(w[k*512+n])
__global__ __launch_bounds__(256) void k_wtrans(const float* __restrict__ w0, const float* __restrict__ w1,
                                                const float* __restrict__ w2, const float* __restrict__ w3,
                                                unsigned short* __restrict__ o0, unsigned short* __restrict__ o1,
                                                unsigned short* __restrict__ o2, unsigned short* __restrict__ o3) {
  const float* w; unsigned short* o;
  switch (blockIdx.y) {
    case 0: w = w0; o = o0; break;
    case 1: w = w1; o = o1; break;
    case 2: w = w2; o = o2; break;
    default: w = w3; o = o3; break;
  }
  int idx = blockIdx.x * 256 + threadIdx.x;   // 0..262143
  int kk = idx >> 9;
  int n  = idx & 511;
  o[n * 512 + kk] = f2bf(w[idx]);
}

// ---- V transpose: v_row[16384][512] -> v_t[b][512][4096], 64x64 LDS tiles ----

__global__ __launch_bounds__(256) void k_vtrans(const unsigned short* __restrict__ vr,
                                                unsigned short* __restrict__ vt) {
  __shared__ unsigned short lds[64 * 66];    // pad 66: bank-friendly
  const int tid = threadIdx.x;
  const int d0 = blockIdx.x * 64;            // 0..448
  const int s0 = blockIdx.y * 64;            // 0..16320 (tile within one batch)
  const int r = tid >> 4;                    // 0..15
  const int c4 = (tid & 15) * 4;             // 0,4,...,60
#pragma unroll
  for (int i = 0; i < 4; ++i) {
    const int row = i * 16 + r;              // s-offset in tile
    ushort4 v = *reinterpret_cast<const ushort4*>(&vr[(size_t)(s0 + row) * 512 + d0 + c4]);
    lds[row * 66 + c4 + 0] = v.x;
    lds[row * 66 + c4 + 1] = v.y;
    lds[row * 66 + c4 + 2] = v.z;
    lds[row * 66 + c4 + 3] = v.w;
  }
  __syncthreads();
  const int b = s0 >> 12;
  const int sin = s0 & 4095;
#pragma unroll
  for (int i = 0; i < 4; ++i) {
    const int drow = i * 16 + r;             // d-offset in tile
    ushort4 o;
    o.x = lds[(c4 + 0) * 66 + drow];
    o.y = lds[(c4 + 1) * 66 + drow];
    o.z = lds[(c4 + 2) * 66 + drow];
    o.w = lds[(c4 + 3) * 66 + drow];
    *reinterpret_cast<ushort4*>(&vt[(size_t)b * 2097152u + (size_t)(d0 + drow) * 4096u
                                    + sin + c4]) = o;
  }
}

// ---------------- shared GEMM body: C[M,N] = A[M,K] * Bt[N,K]^T (+bias) -----
// m97 structure: 128x128 tile, BK=32, 4 waves, global_load_lds width 16,
// mfma_f32_16x16x32_bf16. C frag layout col=lane&15, row=(lane>>4)*4+reg.
// Bijective XCD swizzle (all grids %8==0): consecutive bids are bx-major and
// share the A panel -> keeping them on one XCD makes A re-reads L2 hits.
// EPI: 0=bf16+bias  1=f32(+bias if HAS_BIAS)
// 2=dual KV, BOTH row-major (V transposed later by k_vtrans)
// 3=bf16(exp(v)) only (row-sum by separate k_rowsum — fusing it cost +100us).
// SPLITK: bz picks a kLen K-chunk, f32 partial at CoutF + bz*partStride.

template<int EPI, int HAS_BIAS, int SPLITK>
static __device__ __forceinline__ void gemm_body(
    const unsigned short* __restrict__ A, int lda,
    const unsigned short* __restrict__ Bt, int ldb,
    const float* __restrict__ bias, const float* __restrict__ bias2,
    void* __restrict__ Cout, void* __restrict__ Cout2,
    int ldc, int kLen, int partStride)
{
  __shared__ __align__(16) unsigned short sA[128 * 32];
  __shared__ __align__(16) unsigned short sB[128 * 32];

  // XCD-aware bijective swizzle (nwg % 8 == 0 for every caller)
  const int nx = gridDim.x, ny = gridDim.y;
  const int nwg = nx * ny * gridDim.z;
  const int bid = blockIdx.x + nx * (blockIdx.y + ny * blockIdx.z);
  const int wg = (bid & 7) * (nwg >> 3) + (bid >> 3);
  const int bx = wg % nx;
  const int tmp = wg / nx;
  const int by = tmp % ny;
  const int bz = tmp / ny;

  float* CoutF = (float*)Cout;
  if (SPLITK) {
    A  += (size_t)bz * kLen;
    Bt += (size_t)bz * kLen;
    CoutF += (size_t)bz * partStride;
  }

  const int tid = threadIdx.x;
  const int tileM = by * 128;
  const int tileN = bx * 128;
  const unsigned short* Ab = A + (size_t)tileM * lda;
  const unsigned short* Bb = Bt + (size_t)tileN * ldb;

  f32x4 acc[4][4];
#pragma unroll
  for (int m = 0; m < 4; ++m)
#pragma unroll
    for (int n = 0; n < 4; ++n)
      acc[m][n] = (f32x4){0.f, 0.f, 0.f, 0.f};

  const int lane = tid & 63;
  const int w = tid >> 6;
  const int wr = (w >> 1) * 64;
  const int wc = (w & 1) * 64;
  const int fr = lane & 15;
  const int fk = (lane >> 4) * 8;

  for (int k0 = 0; k0 < kLen; k0 += 32) {
    __syncthreads();
#pragma unroll
    for (int i = 0; i < 2; ++i) {
      int c = tid + i * 256;         // 0..511 (16B chunks)
      int r = c >> 2;
      int cb = (c & 3) * 8;
      __builtin_amdgcn_global_load_lds((const AS1 void*)(Ab + (size_t)r * lda + k0 + cb),
                                       (AS3 void*)(&sA[c * 8]), 16, 0, 0);
      __builtin_amdgcn_global_load_lds((const AS1 void*)(Bb + (size_t)r * ldb + k0 + cb),
                                       (AS3 void*)(&sB[c * 8]), 16, 0, 0);
    }
    __syncthreads();

    bf16x8 af[4], bfr[4];
#pragma unroll
    for (int m = 0; m < 4; ++m)
      af[m] = *reinterpret_cast<const bf16x8*>(&sA[(wr + m * 16 + fr) * 32 + fk]);
#pragma unroll
    for (int n = 0; n < 4; ++n)
      bfr[n] = *reinterpret_cast<const bf16x8*>(&sB[(wc + n * 16 + fr) * 32 + fk]);
#pragma unroll
    for (int m = 0; m < 4; ++m)
#pragma unroll
      for (int n = 0; n < 4; ++n)
        acc[m][n] = __builtin_amdgcn_mfma_f32_16x16x32_bf16(af[m], bfr[n], acc[m][n], 0, 0, 0);
  }

  const int col4 = lane & 15;
  const int rw4 = (lane >> 4) * 4;
#pragma unroll
  for (int n = 0; n < 4; ++n) {
    const int gc = tileN + wc + n * 16 + col4;
    float bval = 0.f;
    if (HAS_BIAS) bval = (EPI == 2) ? (gc < 512 ? bias[gc] : bias2[gc - 512]) : bias[gc];
#pragma unroll
    for (int m = 0; m < 4; ++m) {
      const int gr0 = tileM + wr + m * 16 + rw4;
#pragma unroll
      for (int j = 0; j < 4; ++j) {
        const int gr = gr0 + j;
        float v = acc[m][n][j] + bval;
        if (EPI == 1) {
          CoutF[(size_t)gr * ldc + gc] = v;
        } else if (EPI == 0) {
          ((unsigned short*)Cout)[(size_t)gr * ldc + gc] = f2bf(v);
        } else if (EPI == 3) {
          ((unsigned short*)Cout)[(size_t)gr * ldc + gc] = f2bf(__expf(v));
        } else {  // EPI == 2: dual K | V, both row-major [16384][512]
          if (gc < 512) {
            ((unsigned short*)Cout)[(size_t)gr * 512 + gc] = f2bf(v);
          } else {
            ((unsigned short*)Cout2)[(size_t)gr * 512 + (gc - 512)] = f2bf(v);
          }
        }
      }
    }
  }
}

// ------------- named kernel wrappers (distinct rocprof Kernel_Name) ---------

__global__ __launch_bounds__(256) void k_proj_q(
    const unsigned short* __restrict__ A, const unsigned short* __restrict__ Bt,
    const float* __restrict__ bias, unsigned short* __restrict__ C) {
  gemm_body<0, 1, 0>(A, 512, Bt, 512, bias, nullptr, C, nullptr, 512, 512, 0);
}

__global__ __launch_bounds__(256) void k_proj_kv(
    const unsigned short* __restrict__ A, const unsigned short* __restrict__ Bt,
    const float* __restrict__ biask, const float* __restrict__ biasv,
    unsigned short* __restrict__ K, unsigned short* __restrict__ Vrow) {
  gemm_body<2, 1, 0>(A, 512, Bt, 512, biask, biasv, K, Vrow, 512, 512, 0);
}

__global__ __launch_bounds__(256) void k_sexp(
    const unsigned short* __restrict__ Q, const unsigned short* __restrict__ K,
    unsigned short* __restrict__ E) {
  gemm_body<3, 0, 0>(Q, 512, K, 512, nullptr, nullptr, E, nullptr, 4096, 512, 0);
}

__global__ __launch_bounds__(256) void k_pv(
    const unsigned short* __restrict__ E, const unsigned short* __restrict__ Vt,
    float* __restrict__ part) {
  gemm_body<1, 0, 1>(E, 4096, Vt, 4096, nullptr, nullptr, part, nullptr, 512, 1024, 4096 * 512);
}

__global__ __launch_bounds__(256) void k_oproj(
    const unsigned short* __restrict__ A, const unsigned short* __restrict__ Bt,
    const float* __restrict__ bias, float* __restrict__ C) {
  gemm_body<1, 1, 0>(A, 512, Bt, 512, bias, nullptr, C, nullptr, 512, 512, 0);
}

// ---------------- row sum of E = exp(S): invl[row] = 1 / sum ----------------

__global__ __launch_bounds__(256) void k_rowsum(const unsigned short* __restrict__ E,
                                                float* __restrict__ invl) {
  const int row = blockIdx.x;
  const uint4* p = reinterpret_cast<const uint4*>(E + (size_t)row * 4096);
  const int tid = threadIdx.x;
  float s = 0.f;
#pragma unroll
  for (int i = 0; i < 2; ++i) {
    uint4 u = p[tid + i * 256];
    s += bf2f_lo(u.x) + bf2f_hi(u.x) + bf2f_lo(u.y) + bf2f_hi(u.y)
       + bf2f_lo(u.z) + bf2f_hi(u.z) + bf2f_lo(u.w) + bf2f_hi(u.w);
  }
#pragma unroll
  for (int off = 32; off >= 1; off >>= 1) s += __shfl_xor(s, off);
  __shared__ float reds[4];
  const int wv = tid >> 6, ln = tid & 63;
  if (ln == 0) reds[wv] = s;
  __syncthreads();
  if (tid == 0) {
    float t = reds[0] + reds[1] + reds[2] + reds[3];
    invl[row] = 1.0f / t;
  }
}

// ------- split-K reduce + softmax normalization: ctx = bf16(sum * invl) ------

__global__ __launch_bounds__(256) void k_reduce_ks(const float* __restrict__ part,
                                                   const float* __restrict__ invl,
                                                   unsigned short* __restrict__ out) {
  const int i = blockIdx.x * 256 + threadIdx.x;       // float4 index, 524288 total
  const float4* p = reinterpret_cast<const float4*>(part);
  float4 a = p[i];
  float4 b = p[i + 524288];
  float4 c = p[i + 2 * 524288];
  float4 d = p[i + 3 * 524288];
  const float iv = invl[i >> 7];                      // 128 float4 per 512-col row
  float4 s;
  s.x = ((a.x + b.x) + (c.x + d.x)) * iv;
  s.y = ((a.y + b.y) + (c.y + d.y)) * iv;
  s.z = ((a.z + b.z) + (c.z + d.z)) * iv;
  s.w = ((a.w + b.w) + (c.w + d.w)) * iv;
  ushort4 o;
  o.x = f2bf(s.x); o.y = f2bf(s.y); o.z = f2bf(s.z); o.w = f2bf(s.w);
  reinterpret_cast<ushort4*>(out)[i] = o;
}

// ---------------- launch ----------------

extern "C" void kernel_launch(void* const* d_in, const int* in_sizes, int n_in,
                              void* d_out, int out_size, void* d_ws, size_t ws_size,
                              hipStream_t stream) {
  const float* query  = (const float*)d_in[0];
  const float* target = (const float*)d_in[1];
  const float* wq = (const float*)d_in[2];
  const float* bq = (const float*)d_in[3];
  const float* wk = (const float*)d_in[4];
  const float* bk = (const float*)d_in[5];
  const float* wv = (const float*)d_in[6];
  const float* bv = (const float*)d_in[7];
  const float* wo = (const float*)d_in[8];
  const float* bo = (const float*)d_in[9];
  float* out = (float*)d_out;

  const size_t SZ_BF = (size_t)16384 * 512 * 2;       // 16 MB

  char* ws = (char*)d_ws;
  size_t off = 0;
  unsigned short* query_bf  = (unsigned short*)(ws + off); off += SZ_BF;
  unsigned short* target_bf = (unsigned short*)(ws + off); off += SZ_BF;
  unsigned short* q_bf  = (unsigned short*)(ws + off); off += SZ_BF;
  unsigned short* k_bf  = (unsigned short*)(ws + off); off += SZ_BF;
  unsigned short* v_row = (unsigned short*)(ws + off); off += SZ_BF;  // [16384][512]
  unsigned short* v_t   = (unsigned short*)(ws + off); off += SZ_BF;  // [B][512][4096]
  unsigned short* ctx   = (unsigned short*)(ws + off); off += SZ_BF;
  unsigned short* wq_t  = (unsigned short*)(ws + off); off += 512 * 512 * 2;
  unsigned short* wkv_t = (unsigned short*)(ws + off); off += 2 * 512 * 512 * 2;
  unsigned short* wo_t  = (unsigned short*)(ws + off); off += 512 * 512 * 2;
  unsigned short* Sbuf  = (unsigned short*)(ws + off); off += (size_t)4096 * 4096 * 2;  // 32 MB
  float* invl = (float*)(ws + off); off += 4096 * sizeof(float);
  (void)ws_size;

  // split-K partial buffer (4 x 4096x512 f32 = 32 MB): aliases query_bf/target_bf,
  // which are dead after the projection GEMMs complete (stream-ordered).
  float* part = (float*)ws;

  // 1) inputs -> bf16; weights -> bf16 transposed ([N][K])
  k_f32_to_bf16<<<8192, 256, 0, stream>>>(query,  query_bf,  2097152);
  k_f32_to_bf16<<<8192, 256, 0, stream>>>(target, target_bf, 2097152);
  k_wtrans<<<dim3(1024, 4), 256, 0, stream>>>(wq, wk, wv, wo,
                                              wq_t, wkv_t, wkv_t + 512 * 512, wo_t);

  // 2) projections  (M=16384, K=512); V row-major, then tiled transpose
  k_proj_q<<<dim3(4, 128), 256, 0, stream>>>(query_bf, wq_t, bq, q_bf);
  k_proj_kv<<<dim3(8, 128), 256, 0, stream>>>(target_bf, wkv_t, bk, bv, k_bf, v_row);
  k_vtrans<<<dim3(8, 256), 256, 0, stream>>>(v_row, v_t);

  // 3) per-batch attention
  for (int b = 0; b < 4; ++b) {
    const unsigned short* qb  = q_bf + (size_t)b * 4096 * 512;
    const unsigned short* kb  = k_bf + (size_t)b * 4096 * 512;
    const unsigned short* vtb = v_t  + (size_t)b * 512 * 4096;
    unsigned short* ctxb = ctx + (size_t)b * 4096 * 512;

    // E = exp(Q K^T)  (bf16, plain epilogue)
    k_sexp<<<dim3(32, 32), 256, 0, stream>>>(qb, kb, Sbuf);
    // invl = 1 / row-sum(E)
    k_rowsum<<<4096, 256, 0, stream>>>(Sbuf, invl);
    // partial = E @ V  (split-K x4, f32 partials)
    k_pv<<<dim3(4, 32, 4), 256, 0, stream>>>(Sbuf, vtb, part);
    // ctx = bf16((sum of partials) * invl)
    k_reduce_ks<<<2048, 256, 0, stream>>>(part, invl, ctxb);
  }

  // 4) output projection (f32 out, bias)
  k_oproj<<<dim3(4, 128), 256, 0, stream>>>(ctx, wo_t, bo, out);
}